// Round 3
// baseline (178.851 us; speedup 1.0000x reference)
//
#include <hip/hip_runtime.h>

typedef short  bf16x8 __attribute__((ext_vector_type(8)));
typedef float  f32x4  __attribute__((ext_vector_type(4)));

#define NA   32
#define HID  128
#define TPB  8
#define KSTR 136   // ushort stride for k/v rows: 272B = 16B-aligned, banks ~4-way worst

__device__ __forceinline__ unsigned short f2bf(float f) {
  unsigned int u = __float_as_uint(f);
  return (unsigned short)((u + 0x7FFFu + ((u >> 16) & 1u)) >> 16);  // RNE
}
__device__ __forceinline__ float bf2f(unsigned short s) {
  return __uint_as_float(((unsigned int)s) << 16);
}

// k-index mapping for 16x16x32 MFMA: we CHOOSE k = ks*32 + lg*8 + e for both A and B
// fragments (any bijection is valid as long as A and B agree), so A-frags are 8
// contiguous bf16 -> staging is 2 float4 global loads + 1 b128 LDS write.

__global__ __launch_bounds__(256, 2) void soft_attn_pipe(
    const float* __restrict__ h, const float* __restrict__ msg,
    const float* __restrict__ mask,
    const float* __restrict__ qW, const float* __restrict__ qb,
    const float* __restrict__ kW, const float* __restrict__ kb,
    const float* __restrict__ vW, const float* __restrict__ vb,
    const float* __restrict__ dW, const float* __restrict__ db,
    const float* __restrict__ lnw, const float* __restrict__ lnb,
    float* __restrict__ out)
{
  const int t    = threadIdx.x;
  const int lane = t & 63;
  const int w    = t >> 6;        // wave id: owns output cols [32w, 32w+32) = heads {2w,2w+1}
  const int lm   = lane & 15;
  const int lg   = lane >> 4;
  const int n0   = w * 32;
  const int tok0 = blockIdx.x * TPB;

  __shared__ __align__(16) short          s_msgF[2][8 * 64 * 8];   // 16 KB: msg A-frags, dbuf
  __shared__ __align__(16) unsigned short s_kT[2][NA * KSTR];      // 17 KB: k bf16, dbuf
  __shared__ __align__(16) unsigned short s_vT[2][NA * KSTR];      // 17 KB: v bf16 (relu'd), dbuf
  __shared__ __align__(16) short          s_hF[4 * 64 * 8];        // 4 KB: h A-frags (rows=tokens)
  __shared__ __align__(16) short          s_ctxF[4 * 64 * 8];      // 4 KB: ctx A-frags
  __shared__ __align__(16) float          s_qall[TPB * HID];       // 4 KB
  __shared__ __align__(16) float          s_hall[TPB * HID];       // 4 KB (residual)
  __shared__ __align__(16) float          s_dall[TPB * HID];       // 4 KB

  // ---- prologue staging: h (fp32 + frags), msg token 0 frags ----
  ((f32x4*)s_hall)[t] = ((const f32x4*)(h + (size_t)tok0 * HID))[t];
  {
    const int f = t >> 6, sl = t & 63, m = sl & 15, kg = sl >> 4;
    bf16x8 sv;
#pragma unroll
    for (int e = 0; e < 8; ++e) sv[e] = 0;
    if (m < TPB) {
      const float* hp = h + (size_t)(tok0 + m) * HID + f * 32 + kg * 8;
      const f32x4 x0 = *(const f32x4*)hp;
      const f32x4 x1 = *(const f32x4*)(hp + 4);
#pragma unroll
      for (int e = 0; e < 4; ++e) { sv[e] = (short)f2bf(x0[e]); sv[4 + e] = (short)f2bf(x1[e]); }
    }
    ((bf16x8*)s_hF)[t] = sv;
  }
#pragma unroll
  for (int j = 0; j < 2; ++j) {
    const int s = t + j * 256, f = s >> 6, sl = s & 63, m = sl & 15, kg = sl >> 4;
    const int mt = f >> 2, ks = f & 3;
    const float* mp = msg + (size_t)tok0 * (NA * HID) + (mt * 16 + m) * HID + ks * 32 + kg * 8;
    const f32x4 x0 = *(const f32x4*)mp;
    const f32x4 x1 = *(const f32x4*)(mp + 4);
    bf16x8 sv;
#pragma unroll
    for (int e = 0; e < 4; ++e) { sv[e] = (short)f2bf(x0[e]); sv[4 + e] = (short)f2bf(x1[e]); }
    ((bf16x8*)(&s_msgF[0][0]))[s] = sv;
  }

  // ---- weight fragments (persistent for k/v; transient Bq) ----
  bf16x8 Bq[2][4], Bk[2][4], Bv[2][4];
  float qb2[2], kb2[2], vb2[2];
#pragma unroll
  for (int nt = 0; nt < 2; ++nt) {
    const int col = n0 + nt * 16 + lm;
    qb2[nt] = qb[col]; kb2[nt] = kb[col]; vb2[nt] = vb[col];
#pragma unroll
    for (int ks = 0; ks < 4; ++ks) {
      bf16x8 bq, bk, bv;
#pragma unroll
      for (int e = 0; e < 8; ++e) {
        const size_t r = (size_t)(ks * 32 + lg * 8 + e) * HID + col;
        bq[e] = (short)f2bf(qW[r]); bk[e] = (short)f2bf(kW[r]); bv[e] = (short)f2bf(vW[r]);
      }
      Bq[nt][ks] = bq; Bk[nt][ks] = bk; Bv[nt][ks] = bv;
    }
  }

  // ---- initial P prefetch: token 1 ----  P[p] holds token T with p = T&1
  f32x4 P[2][2][2];
#pragma unroll
  for (int j = 0; j < 2; ++j) {
    const int f = j * 4 + w, mt = f >> 2, ks = f & 3;
    const float* mp = msg + (size_t)(tok0 + 1) * (NA * HID) + (mt * 16 + lm) * HID + ks * 32 + lg * 8;
    P[1][j][0] = *(const f32x4*)mp; P[1][j][1] = *(const f32x4*)(mp + 4);
  }
  __syncthreads();

  // ---- batched q projection for all TPB tokens ----
  {
    f32x4 accq[2];
#pragma unroll
    for (int nt = 0; nt < 2; ++nt) accq[nt] = (f32x4){qb2[nt], qb2[nt], qb2[nt], qb2[nt]};
#pragma unroll
    for (int ks = 0; ks < 4; ++ks) {
      const bf16x8 a = ((const bf16x8*)s_hF)[ks * 64 + lane];
#pragma unroll
      for (int nt = 0; nt < 2; ++nt)
        accq[nt] = __builtin_amdgcn_mfma_f32_16x16x32_bf16(a, Bq[nt][ks], accq[nt], 0, 0, 0);
    }
#pragma unroll
    for (int nt = 0; nt < 2; ++nt)
#pragma unroll
      for (int r = 0; r < 4; ++r) {
        const int row = lg * 4 + r;
        if (row < TPB) s_qall[row * HID + n0 + nt * 16 + lm] = accq[nt][r];
      }
  }

  // ---- pipelined main loop: prefetch(t+2) | stage(t+1) | k/v-MFMA(t) | attn(t-1) ----
#pragma unroll
  for (int it = 0; it <= TPB; ++it) {
    const int cur = it & 1, nxt = cur ^ 1;   // nxt == (it+1)&1 == (it-1)&1

    if (it + 2 < TPB) {  // (b) prefetch msg token it+2 -> P[cur]
#pragma unroll
      for (int j = 0; j < 2; ++j) {
        const int f = j * 4 + w, mt = f >> 2, ks = f & 3;
        const float* mp = msg + (size_t)(tok0 + it + 2) * (NA * HID) + (mt * 16 + lm) * HID + ks * 32 + lg * 8;
        P[cur][j][0] = *(const f32x4*)mp; P[cur][j][1] = *(const f32x4*)(mp + 4);
      }
    }
    if (it + 1 < TPB) {  // (a) stage token it+1 from P[nxt] -> s_msgF[nxt]
#pragma unroll
      for (int j = 0; j < 2; ++j) {
        const int f = j * 4 + w;
        bf16x8 sv;
#pragma unroll
        for (int e = 0; e < 4; ++e) {
          sv[e]     = (short)f2bf(P[nxt][j][0][e]);
          sv[4 + e] = (short)f2bf(P[nxt][j][1][e]);
        }
        ((bf16x8*)(&s_msgF[nxt][0]))[f * 64 + lane] = sv;
      }
    }
    if (it < TPB) {      // (c) k/v projection for token it
      bf16x8 A[2][4];
#pragma unroll
      for (int mt = 0; mt < 2; ++mt)
#pragma unroll
        for (int ks = 0; ks < 4; ++ks)
          A[mt][ks] = ((const bf16x8*)(&s_msgF[cur][0]))[(mt * 4 + ks) * 64 + lane];
      f32x4 ak[2][2], av[2][2];
#pragma unroll
      for (int mt = 0; mt < 2; ++mt)
#pragma unroll
        for (int nt = 0; nt < 2; ++nt) {
          ak[mt][nt] = (f32x4){kb2[nt], kb2[nt], kb2[nt], kb2[nt]};
          av[mt][nt] = (f32x4){vb2[nt], vb2[nt], vb2[nt], vb2[nt]};
        }
#pragma unroll
      for (int ks = 0; ks < 4; ++ks)
#pragma unroll
        for (int mt = 0; mt < 2; ++mt)
#pragma unroll
          for (int nt = 0; nt < 2; ++nt) {
            ak[mt][nt] = __builtin_amdgcn_mfma_f32_16x16x32_bf16(A[mt][ks], Bk[nt][ks], ak[mt][nt], 0, 0, 0);
            av[mt][nt] = __builtin_amdgcn_mfma_f32_16x16x32_bf16(A[mt][ks], Bv[nt][ks], av[mt][nt], 0, 0, 0);
          }
#pragma unroll
      for (int mt = 0; mt < 2; ++mt)
#pragma unroll
        for (int nt = 0; nt < 2; ++nt) {
          const int col = n0 + nt * 16 + lm;
#pragma unroll
          for (int r = 0; r < 4; ++r) {
            const int row = mt * 16 + lg * 4 + r;
            s_kT[cur][row * KSTR + col] = f2bf(ak[mt][nt][r]);
            s_vT[cur][row * KSTR + col] = f2bf(fmaxf(av[mt][nt][r], 0.f));
          }
        }
    }
    if (it > 0) {        // (d) attention for token it-1 (k/v in buffer nxt)
      const int tokA = tok0 + it - 1;
      const int hh = lane >> 5, a = lane & 31;
      const int colh = n0 + hh * 16;
      const f32x4* qr = (const f32x4*)(s_qall + (it - 1) * HID + colh);
      const bf16x8 k0 = *(const bf16x8*)&s_kT[nxt][a * KSTR + colh];
      const bf16x8 k1 = *(const bf16x8*)&s_kT[nxt][a * KSTR + colh + 8];
      const f32x4 q0 = qr[0], q1 = qr[1], q2 = qr[2], q3 = qr[3];
      float sc = 0.f;
#pragma unroll
      for (int e = 0; e < 4; ++e) {
        sc = fmaf(q0[e], bf2f((unsigned short)k0[e]), sc);
        sc = fmaf(q1[e], bf2f((unsigned short)k0[4 + e]), sc);
        sc = fmaf(q2[e], bf2f((unsigned short)k1[e]), sc);
        sc = fmaf(q3[e], bf2f((unsigned short)k1[4 + e]), sc);
      }
      const float mk = mask[(size_t)tokA * NA + a];
      sc = sc * 0.25f * mk;
      if (sc == 0.0f) sc = -1000000.0f;   // exact reference semantics
      float mx = sc;
#pragma unroll
      for (int off = 16; off; off >>= 1) mx = fmaxf(mx, __shfl_xor(mx, off));
      const float ex = __expf(sc - mx);
      float sm = ex;
#pragma unroll
      for (int off = 16; off; off >>= 1) sm += __shfl_xor(sm, off);
      const float p = ex / sm * mk;       // this lane's p[head=2w+hh][a], stays in-register
      // PV: lane -> ctx partial for col = colh+lm over a-half `half`
      const int half = (lane >> 4) & 1;
      const int colv = colh + lm;
      float ctx = 0.f;
#pragma unroll
      for (int i = 0; i < 16; ++i) {
        const float pa = __shfl(p, (lane & 32) + half * 16 + i);
        ctx = fmaf(pa, bf2f(s_vT[nxt][(half * 16 + i) * KSTR + colv]), ctx);
      }
      ctx += __shfl_xor(ctx, 16);
      if (half == 0) {   // write ctx bf16 A-frag (row = token)
        const int col = colv, tk = it - 1;
        ((unsigned short*)s_ctxF)[((col >> 5) * 64 + tk + ((col & 31) >> 3) * 16) * 8 + (col & 7)] = f2bf(ctx);
      }
    }
    __syncthreads();
  }

  // ---- batched d projection ----
  {
    bf16x8 Bd[2][4];
    float db2[2];
#pragma unroll
    for (int nt = 0; nt < 2; ++nt) {
      const int col = n0 + nt * 16 + lm;
      db2[nt] = db[col];
#pragma unroll
      for (int ks = 0; ks < 4; ++ks) {
        bf16x8 bd;
#pragma unroll
        for (int e = 0; e < 8; ++e)
          bd[e] = (short)f2bf(dW[(size_t)(ks * 32 + lg * 8 + e) * HID + col]);
        Bd[nt][ks] = bd;
      }
    }
    f32x4 accd[2];
#pragma unroll
    for (int nt = 0; nt < 2; ++nt) accd[nt] = (f32x4){db2[nt], db2[nt], db2[nt], db2[nt]};
#pragma unroll
    for (int ks = 0; ks < 4; ++ks) {
      const bf16x8 a = ((const bf16x8*)s_ctxF)[ks * 64 + lane];
#pragma unroll
      for (int nt = 0; nt < 2; ++nt)
        accd[nt] = __builtin_amdgcn_mfma_f32_16x16x32_bf16(a, Bd[nt][ks], accd[nt], 0, 0, 0);
    }
#pragma unroll
    for (int nt = 0; nt < 2; ++nt)
#pragma unroll
      for (int r = 0; r < 4; ++r) {
        const int row = lg * 4 + r;
        if (row < TPB) s_dall[row * HID + n0 + nt * 16 + lm] = accd[nt][r];
      }
  }
  __syncthreads();

  // ---- residual + layernorm (32 lanes per token row) ----
  {
    const int row = t >> 5, seg = t & 31;
    const f32x4 xd = *(const f32x4*)(s_dall + row * HID + seg * 4);
    const f32x4 xh = *(const f32x4*)(s_hall + row * HID + seg * 4);
    float x[4];
    float s1 = 0.f, s2 = 0.f;
#pragma unroll
    for (int e = 0; e < 4; ++e) { x[e] = xd[e] + xh[e]; s1 += x[e]; s2 += x[e] * x[e]; }
#pragma unroll
    for (int off = 16; off; off >>= 1) { s1 += __shfl_xor(s1, off); s2 += __shfl_xor(s2, off); }
    const float u   = s1 * (1.f / 128.f);
    const float var = s2 * (1.f / 128.f) - u * u;
    const float rs  = rsqrtf(var + 1e-12f);
    const f32x4 w4 = *(const f32x4*)(lnw + seg * 4);
    const f32x4 b4 = *(const f32x4*)(lnb + seg * 4);
    f32x4 y;
#pragma unroll
    for (int e = 0; e < 4; ++e) y[e] = w4[e] * ((x[e] - u) * rs) + b4[e];
    *(f32x4*)(out + (size_t)(tok0 + row) * HID + seg * 4) = y;
  }
}

extern "C" void kernel_launch(void* const* d_in, const int* in_sizes, int n_in,
                              void* d_out, int out_size, void* d_ws, size_t ws_size,
                              hipStream_t stream) {
  const float* h    = (const float*)d_in[0];
  const float* msg  = (const float*)d_in[1];
  const float* mask = (const float*)d_in[2];
  const float* qW   = (const float*)d_in[3];
  const float* qb   = (const float*)d_in[4];
  const float* kW   = (const float*)d_in[5];
  const float* kb   = (const float*)d_in[6];
  const float* vW   = (const float*)d_in[7];
  const float* vb   = (const float*)d_in[8];
  const float* dW   = (const float*)d_in[9];
  const float* db   = (const float*)d_in[10];
  const float* lnw  = (const float*)d_in[11];
  const float* lnb  = (const float*)d_in[12];
  float* out = (float*)d_out;

  const int n_tokens = in_sizes[0] / HID;   // 16384
  const int nblocks  = n_tokens / TPB;      // 2048
  soft_attn_pipe<<<nblocks, 256, 0, stream>>>(
      h, msg, mask, qW, qb, kW, kb, vW, vb, dW, db, lnw, lnb, out);
}